// Round 5
// baseline (264.677 us; speedup 1.0000x reference)
//
#include <hip/hip_runtime.h>
#include <stdint.h>

#define B_ 8
#define C_ 256
#define N_ 2048
#define HC 128

typedef float f32x4 __attribute__((ext_vector_type(4)));
typedef short s16x8 __attribute__((ext_vector_type(8)));

__device__ __forceinline__ unsigned short f2bf(float f){
  union { float f; unsigned u; } v; v.f = f;
  unsigned r = v.u + 0x7FFF + ((v.u >> 16) & 1u);
  return (unsigned short)(r >> 16);
}
__device__ __forceinline__ float bf2f(unsigned short u){
  union { unsigned u; float f; } v; v.u = ((unsigned)u) << 16;
  return v.f;
}

// ---------------- prep: weights -> bf16, BN affine fold ----------------
struct PrepArgs {
  const float *s0,*s1,*s2,*s3,*s4,*s5;
  unsigned short *d0,*d1,*d2,*d3,*d4,*d5;
  const float *b1,*g1,*be1,*m1,*v1;
  const float *b2,*g2,*be2,*m2,*v2;
  float *sc1,*sh1,*sc2,*sh2;
};

__global__ __launch_bounds__(256) void k_prep(PrepArgs a){
  int gid = blockIdx.x*256 + threadIdx.x;
  const int S0=65536, S1=131072, S2=196608, S3=229376, S4=245760, S5=278528;
  if (gid < S0)      a.d0[gid]    = f2bf(a.s0[gid]);
  else if (gid < S1) a.d1[gid-S0] = f2bf(a.s1[gid-S0]);
  else if (gid < S2) a.d2[gid-S1] = f2bf(a.s2[gid-S1]);
  else if (gid < S3) a.d3[gid-S2] = f2bf(a.s3[gid-S2]);
  else if (gid < S4) a.d4[gid-S3] = f2bf(a.s4[gid-S3]);
  else if (gid < S5) a.d5[gid-S4] = f2bf(a.s5[gid-S4]);
  else if (gid < S5+128){
    int o = gid - S5;
    float inv = a.g1[o] * rsqrtf(a.v1[o] + 1e-5f);
    a.sc1[o] = inv;
    a.sh1[o] = a.b1[o]*inv + a.be1[o] - a.m1[o]*inv;
  } else if (gid < S5+256){
    int o = gid - S5 - 128;
    float inv = a.g2[o] * rsqrtf(a.v2[o] + 1e-5f);
    a.sc2[o] = inv;
    a.sh2[o] = a.b2[o]*inv + a.be2[o] - a.m2[o]*inv;
  }
}

// ---------------- x [B][C][N] f32 -> xn [B][N][C] bf16 ----------------
__global__ __launch_bounds__(256) void k_transpose_x(const float* __restrict__ x,
                                                     unsigned short* __restrict__ xn){
  __shared__ float lds[64][65];
  int b = blockIdx.z, ct = blockIdx.y, nt = blockIdx.x;
  int n0 = nt*64, c0 = ct*64;
  const float* xb = x + (size_t)b*C_*N_;
  int tn = threadIdx.x & 63, tc0 = threadIdx.x >> 6;
  #pragma unroll
  for (int cc = tc0; cc < 64; cc += 4)
    lds[tn][cc] = xb[(size_t)(c0+cc)*N_ + n0 + tn];
  __syncthreads();
  unsigned short* xnb = xn + (size_t)b*N_*C_;
  int cl = threadIdx.x & 63, nl0 = threadIdx.x >> 6;
  #pragma unroll
  for (int nl = nl0; nl < 64; nl += 4)
    xnb[(size_t)(n0+nl)*C_ + c0 + cl] = f2bf(lds[nl][cl]);
}

// ---------------- QKV GEMM: xn @ W^T + b ----------------
__global__ __launch_bounds__(256) void k_qkv(
    const unsigned short* __restrict__ xn,
    const unsigned short* __restrict__ wqb, const unsigned short* __restrict__ wkb,
    const unsigned short* __restrict__ wvb,
    const float* __restrict__ bq, const float* __restrict__ bk, const float* __restrict__ bv,
    unsigned short* __restrict__ Qn, unsigned short* __restrict__ Kn,
    unsigned short* __restrict__ Vc)
{
  __shared__ unsigned short Alds[64][256];
  __shared__ unsigned short Tlds[64][260];
  int b = blockIdx.y, nt = blockIdx.x, z = blockIdx.z;
  int nb = nt*64;
  const unsigned short* W = (z==0) ? wqb : (z==1 ? wkb : wvb);
  const float* bias = (z==0) ? bq : (z==1 ? bk : bv);
  const unsigned short* Ab = xn + ((size_t)b*N_ + nb)*C_;
  for (int i = threadIdx.x; i < 64*32; i += 256){
    int r = i >> 5, cv = i & 31;
    *(s16x8*)&Alds[r][(cv*8) ^ ((r&7)<<3)] = *(const s16x8*)&Ab[(size_t)r*C_ + cv*8];
  }
  __syncthreads();
  int w = threadIdx.x >> 6, l = threadIdx.x & 63, lr = l & 15, lq = l >> 4;
  f32x4 acc[16];
  f32x4 zero = {0.f,0.f,0.f,0.f};
  #pragma unroll
  for (int i=0;i<16;i++) acc[i] = zero;
  #pragma unroll
  for (int ks = 0; ks < 8; ks++){
    s16x8 a = *(const s16x8*)&Alds[16*w + lr][(32*ks + 8*lq) ^ ((lr&7)<<3)];
    #pragma unroll
    for (int ct = 0; ct < 16; ct++){
      s16x8 bw = *(const s16x8*)&W[(size_t)(16*ct + lr)*C_ + 32*ks + 8*lq];
      acc[ct] = __builtin_amdgcn_mfma_f32_16x16x32_bf16(a, bw, acc[ct], 0, 0, 0);
    }
  }
  if (z < 2){
    unsigned short* ob = (z==0 ? Qn : Kn) + ((size_t)b*N_ + nb)*C_;
    #pragma unroll
    for (int ct = 0; ct < 16; ct++){
      int o = 16*ct + lr;
      float bi = bias[o];
      #pragma unroll
      for (int r = 0; r < 4; r++){
        int row = 16*w + 4*lq + r;
        ob[(size_t)row*C_ + o] = f2bf(acc[ct][r] + bi);
      }
    }
  } else {
    #pragma unroll
    for (int ct = 0; ct < 16; ct++){
      int o = 16*ct + lr;
      float bi = bias[o];
      #pragma unroll
      for (int r = 0; r < 4; r++)
        Tlds[16*w + 4*lq + r][o] = f2bf(acc[ct][r] + bi);
    }
    __syncthreads();
    unsigned short* vb = Vc + (size_t)b*C_*N_;
    int j = threadIdx.x & 63, o0 = threadIdx.x >> 6;
    #pragma unroll
    for (int o = o0; o < 256; o += 4)
      vb[(size_t)o*N_ + nb + j] = Tlds[j][o];
  }
}

// ---------------- attention: KVBLK=32, 4-way m-split, 4 blocks/CU ----------------
// grid (32 nt, 8 b, 4 mh), 256 thr, 36.8KB LDS + VGPR<=128 -> 4 blocks/CU
// (16 waves/CU). Co-resident blocks interleave their stall phases.
// P = exp(S*beta) raw (f32-safe); unnormalized bf16 partials -> k_merge.
__global__ __launch_bounds__(256, 4) void k_attn(
    const unsigned short* __restrict__ Qn, const unsigned short* __restrict__ Kn,
    const unsigned short* __restrict__ Vc, const float* __restrict__ beta,
    unsigned short* __restrict__ Opb, float* __restrict__ Ls)
{
  __shared__ unsigned short Klds[32][256];
  __shared__ unsigned short Vt[256][32];
  __shared__ unsigned short Plds[4][16][32];
  int b = blockIdx.y, nt = blockIdx.x, mh = blockIdx.z;
  int nb = nt*64;
  const unsigned short* Qb = Qn + (size_t)b*N_*C_;
  const unsigned short* Kb = Kn + (size_t)b*N_*C_;
  const unsigned short* Vb = Vc + (size_t)b*C_*N_;
  const float* betab = beta + (size_t)b*N_*N_;
  int w = threadIdx.x >> 6, l = threadIdx.x & 63, lr = l & 15, lq = l >> 4;

  // Q fragments (regs, whole kernel)
  s16x8 qf[8];
  {
    const unsigned short* qrow = Qb + (size_t)(nb + 16*w + lr)*C_;
    #pragma unroll
    for (int ks = 0; ks < 8; ks++)
      qf[ks] = *(const s16x8*)&qrow[32*ks + 8*lq];
  }
  f32x4 zero = {0.f,0.f,0.f,0.f};
  f32x4 oacc[16];
  #pragma unroll
  for (int i=0;i<16;i++) oacc[i] = zero;
  float psum[4] = {0.f,0.f,0.f,0.f};

  for (int mt = 0; mt < 16; mt++){
    int mb = mh*512 + mt*32;
    // stage K [32][256] (swizzled), coalesced 16B loads
    for (int i = threadIdx.x; i < 32*32; i += 256){
      int r = i >> 5, cv = i & 31;
      *(s16x8*)&Klds[r][(cv*8) ^ ((r&7)<<3)] = *(const s16x8*)&Kb[(size_t)(mb+r)*C_ + cv*8];
    }
    // stage Vt = V c-major tile [256][32] (swizzled)
    for (int i = threadIdx.x; i < 256*4; i += 256){
      int c = i >> 2, mv = i & 3;
      *(s16x8*)&Vt[c][(mv*8) ^ ((c&3)<<3)] = *(const s16x8*)&Vb[(size_t)c*N_ + mb + mv*8];
    }
    __syncthreads();

    // beta for this tile (issued early, consumed after QK^T)
    float be[2][4];
    #pragma unroll
    for (int t4=0;t4<2;t4++)
      #pragma unroll
      for (int r=0;r<4;r++)
        be[t4][r] = betab[(size_t)(nb + 16*w + 4*lq + r)*N_ + mb + 16*t4 + lr];

    // S = Q K^T from LDS
    f32x4 s_[2];
    s_[0] = zero; s_[1] = zero;
    #pragma unroll
    for (int ks=0;ks<8;ks++){
      #pragma unroll
      for (int t4=0;t4<2;t4++){
        s16x8 bk_ = *(const s16x8*)&Klds[16*t4 + lr][(32*ks + 8*lq) ^ ((lr&7)<<3)];
        s_[t4] = __builtin_amdgcn_mfma_f32_16x16x32_bf16(qf[ks], bk_, s_[t4], 0, 0, 0);
      }
    }
    // P = exp(S*beta); per-lane row-sums; pack to per-wave Plds
    #pragma unroll
    for (int t4=0;t4<2;t4++)
      #pragma unroll
      for (int r=0;r<4;r++){
        float p_ = __expf(s_[t4][r] * be[t4][r]);
        psum[r] += p_;
        int i_ = 4*lq + r;
        Plds[w][i_][(16*t4 + lr) ^ ((i_&3)<<3)] = f2bf(p_);
      }
    // PV: O += P * V from LDS (K-dim = 32 -> single A-frag)
    {
      s16x8 ap_ = *(const s16x8*)&Plds[w][lr][(8*lq) ^ ((lr&3)<<3)];
      #pragma unroll
      for (int ct=0; ct<16; ct++){
        int c = 16*ct + lr;
        s16x8 bv_ = *(const s16x8*)&Vt[c][(8*lq) ^ ((c&3)<<3)];
        oacc[ct] = __builtin_amdgcn_mfma_f32_16x16x32_bf16(ap_, bv_, oacc[ct], 0,0,0);
      }
    }
    __syncthreads();
  }

  // reduce row-sums across the 16-lane lr group (lanes share lq -> same rows)
  #pragma unroll
  for (int r=0;r<4;r++){
    #pragma unroll
    for (int d=1; d<16; d<<=1) psum[r] += __shfl_xor(psum[r], d, 64);
  }
  // store unnormalized partials as bf16 (normalization divides out quant noise)
  unsigned short* Ob = Opb + ((size_t)mh*8 + b)*(size_t)N_*C_;
  #pragma unroll
  for (int ct=0; ct<16; ct++)
    #pragma unroll
    for (int r=0;r<4;r++)
      Ob[(size_t)(nb + 16*w + 4*lq + r)*C_ + 16*ct + lr] = f2bf(oacc[ct][r]);
  if (lr == 0){
    float* Lb = Ls + ((size_t)mh*8 + b)*N_;
    #pragma unroll
    for (int r=0;r<4;r++) Lb[nb + 16*w + 4*lq + r] = psum[r];
  }
}

// ---------------- merge the four m-quarters, normalize, -> Mn bf16 ----------------
__global__ __launch_bounds__(256) void k_merge(
    const unsigned short* __restrict__ Opb, const float* __restrict__ Ls,
    unsigned short* __restrict__ Mn)
{
  int gid = blockIdx.x*256 + threadIdx.x;          // 8*2048*32 short8 chunks
  int c8 = gid & 31, n = (gid >> 5) & 2047, b = gid >> 16;
  size_t base = ((size_t)b*N_ + n)*C_ + c8*8;
  const size_t PS = (size_t)8*N_*C_;
  float acc[8] = {0.f,0.f,0.f,0.f,0.f,0.f,0.f,0.f};
  float lsum = 0.f;
  #pragma unroll
  for (int m=0;m<4;m++){
    s16x8 v = *(const s16x8*)&Opb[(size_t)m*PS + base];
    #pragma unroll
    for (int j=0;j<8;j++) acc[j] += bf2f((unsigned short)v[j]);
    lsum += Ls[((size_t)m*8 + b)*N_ + n];
  }
  float inv = 1.f / lsum;
  s16x8 o;
  #pragma unroll
  for (int j=0;j<8;j++) o[j] = (short)f2bf(acc[j] * inv);
  *(s16x8*)&Mn[base] = o;
}

// ---------------- generic NT GEMM: out[n][o] = epi(sum_c A[n][c] W[o][c]) ----------------
template<int CIN, int COUT, int MODE>
__global__ __launch_bounds__(256) void k_gemm(
    const unsigned short* __restrict__ A, const unsigned short* __restrict__ W,
    const float* __restrict__ bias, const float* __restrict__ sc,
    const float* __restrict__ sh, unsigned short* __restrict__ out)
{
  __shared__ unsigned short Alds[64][CIN];
  int b = blockIdx.y, nt = blockIdx.x, nb = nt*64;
  const unsigned short* Ab = A + ((size_t)b*N_ + nb)*CIN;
  constexpr int PR = CIN/8;
  for (int i = threadIdx.x; i < 64*PR; i += 256){
    int r = i / PR, cv = i % PR;
    *(s16x8*)&Alds[r][(cv*8) ^ ((r&7)<<3)] = *(const s16x8*)&Ab[(size_t)r*CIN + cv*8];
  }
  __syncthreads();
  int w = threadIdx.x >> 6, l = threadIdx.x & 63, lr = l & 15, lq = l >> 4;
  constexpr int NT = COUT/16;
  f32x4 acc[NT];
  f32x4 zero = {0.f,0.f,0.f,0.f};
  #pragma unroll
  for (int i=0;i<NT;i++) acc[i] = zero;
  #pragma unroll
  for (int ks = 0; ks < CIN/32; ks++){
    s16x8 a = *(const s16x8*)&Alds[16*w + lr][(32*ks + 8*lq) ^ ((lr&7)<<3)];
    #pragma unroll
    for (int ct = 0; ct < NT; ct++){
      s16x8 bw = *(const s16x8*)&W[(size_t)(16*ct + lr)*CIN + 32*ks + 8*lq];
      acc[ct] = __builtin_amdgcn_mfma_f32_16x16x32_bf16(a, bw, acc[ct], 0, 0, 0);
    }
  }
  unsigned short* ob = out + ((size_t)b*N_ + nb)*COUT;
  #pragma unroll
  for (int ct = 0; ct < NT; ct++){
    int o = 16*ct + lr;
    float bi = (MODE==0) ? bias[o] : 0.f;
    float s_ = (MODE==1) ? sc[o] : 0.f;
    float h_ = (MODE==1) ? sh[o] : 0.f;
    #pragma unroll
    for (int r = 0; r < 4; r++){
      int row = 16*w + 4*lq + r;
      float y;
      if (MODE==1) y = fmaxf(acc[ct][r]*s_ + h_, 0.f);
      else         y = acc[ct][r] + bi;
      ob[(size_t)row*COUT + o] = f2bf(y);
    }
  }
}

// ---------------- final: out[b][o][n] = x + h2n @ w3^T + b3 ----------------
__global__ __launch_bounds__(256) void k_mlp3(
    const unsigned short* __restrict__ A, const unsigned short* __restrict__ W,
    const float* __restrict__ b3, const float* __restrict__ x,
    float* __restrict__ out)
{
  __shared__ unsigned short Alds[64][128];
  __shared__ float Dlds[64][257];
  int b = blockIdx.y, nt = blockIdx.x, nb = nt*64;
  const unsigned short* Ab = A + ((size_t)b*N_ + nb)*HC;
  for (int i = threadIdx.x; i < 64*16; i += 256){
    int r = i >> 4, cv = i & 15;
    *(s16x8*)&Alds[r][(cv*8) ^ ((r&7)<<3)] = *(const s16x8*)&Ab[(size_t)r*HC + cv*8];
  }
  __syncthreads();
  int w = threadIdx.x >> 6, l = threadIdx.x & 63, lr = l & 15, lq = l >> 4;
  f32x4 acc[16];
  f32x4 zero = {0.f,0.f,0.f,0.f};
  #pragma unroll
  for (int i=0;i<16;i++) acc[i] = zero;
  #pragma unroll
  for (int ks = 0; ks < 4; ks++){
    s16x8 a = *(const s16x8*)&Alds[16*w + lr][(32*ks + 8*lq) ^ ((lr&7)<<3)];
    #pragma unroll
    for (int ct = 0; ct < 16; ct++){
      s16x8 bw = *(const s16x8*)&W[(size_t)(16*ct + lr)*HC + 32*ks + 8*lq];
      acc[ct] = __builtin_amdgcn_mfma_f32_16x16x32_bf16(a, bw, acc[ct], 0, 0, 0);
    }
  }
  #pragma unroll
  for (int ct = 0; ct < 16; ct++){
    int o = 16*ct + lr;
    float bi = b3[o];
    #pragma unroll
    for (int r = 0; r < 4; r++)
      Dlds[16*w + 4*lq + r][o] = acc[ct][r] + bi;
  }
  __syncthreads();
  const float* xb = x + (size_t)b*C_*N_;
  float* ob = out + (size_t)b*C_*N_;
  int j = threadIdx.x & 63, o0 = threadIdx.x >> 6;
  #pragma unroll
  for (int o = o0; o < 256; o += 4)
    ob[(size_t)o*N_ + nb + j] = xb[(size_t)o*N_ + nb + j] + Dlds[j][o];
}

extern "C" void kernel_launch(void* const* d_in, const int* in_sizes, int n_in,
                              void* d_out, int out_size, void* d_ws, size_t ws_size,
                              hipStream_t stream)
{
  const float* x    = (const float*)d_in[0];
  const float* beta = (const float*)d_in[1];
  const float* wq = (const float*)d_in[2];  const float* bq = (const float*)d_in[3];
  const float* wk = (const float*)d_in[4];  const float* bk = (const float*)d_in[5];
  const float* wv = (const float*)d_in[6];  const float* bv = (const float*)d_in[7];
  const float* w1 = (const float*)d_in[8];  const float* b1 = (const float*)d_in[9];
  const float* g1 = (const float*)d_in[10]; const float* be1= (const float*)d_in[11];
  const float* m1 = (const float*)d_in[12]; const float* v1 = (const float*)d_in[13];
  const float* w2 = (const float*)d_in[14]; const float* b2 = (const float*)d_in[15];
  const float* g2 = (const float*)d_in[16]; const float* be2= (const float*)d_in[17];
  const float* m2 = (const float*)d_in[18]; const float* v2 = (const float*)d_in[19];
  const float* w3 = (const float*)d_in[20]; const float* b3 = (const float*)d_in[21];

  char* p = (char*)d_ws;
  auto alloc = [&](size_t n){ char* r = p; p += (n + 255) & ~(size_t)255; return r; };
  unsigned short* xn  = (unsigned short*)alloc((size_t)B_*N_*C_*2);
  unsigned short* Qn  = (unsigned short*)alloc((size_t)B_*N_*C_*2);
  unsigned short* Kn  = (unsigned short*)alloc((size_t)B_*N_*C_*2);
  unsigned short* Vc  = (unsigned short*)alloc((size_t)B_*N_*C_*2);
  unsigned short* Mn  = (unsigned short*)alloc((size_t)B_*N_*C_*2);
  unsigned short* h1n = (unsigned short*)alloc((size_t)B_*N_*HC*2);
  unsigned short* h2n = (unsigned short*)alloc((size_t)B_*N_*HC*2);
  unsigned short* Opb = (unsigned short*)alloc((size_t)4*B_*N_*C_*2);
  float* Ls = (float*)alloc((size_t)4*B_*N_*4);
  unsigned short* wqb = (unsigned short*)alloc(65536*2);
  unsigned short* wkb = (unsigned short*)alloc(65536*2);
  unsigned short* wvb = (unsigned short*)alloc(65536*2);
  unsigned short* w1b = (unsigned short*)alloc(32768*2);
  unsigned short* w2b = (unsigned short*)alloc(16384*2);
  unsigned short* w3b = (unsigned short*)alloc(32768*2);
  float* sc1 = (float*)alloc(128*4);
  float* sh1 = (float*)alloc(128*4);
  float* sc2 = (float*)alloc(128*4);
  float* sh2 = (float*)alloc(128*4);

  PrepArgs pa;
  pa.s0 = wq; pa.s1 = wk; pa.s2 = wv; pa.s3 = w1; pa.s4 = w2; pa.s5 = w3;
  pa.d0 = wqb; pa.d1 = wkb; pa.d2 = wvb; pa.d3 = w1b; pa.d4 = w2b; pa.d5 = w3b;
  pa.b1 = b1; pa.g1 = g1; pa.be1 = be1; pa.m1 = m1; pa.v1 = v1;
  pa.b2 = b2; pa.g2 = g2; pa.be2 = be2; pa.m2 = m2; pa.v2 = v2;
  pa.sc1 = sc1; pa.sh1 = sh1; pa.sc2 = sc2; pa.sh2 = sh2;

  k_prep<<<dim3(1089), dim3(256), 0, stream>>>(pa);
  k_transpose_x<<<dim3(32, 4, 8), dim3(256), 0, stream>>>(x, xn);
  k_qkv<<<dim3(32, 8, 3), dim3(256), 0, stream>>>(xn, wqb, wkb, wvb, bq, bk, bv, Qn, Kn, Vc);
  k_attn<<<dim3(32, 8, 4), dim3(256), 0, stream>>>(Qn, Kn, Vc, beta, Opb, Ls);
  k_merge<<<dim3(2048), dim3(256), 0, stream>>>(Opb, Ls, Mn);
  k_gemm<256,128,1><<<dim3(32, 8), dim3(256), 0, stream>>>(Mn, w1b, b1, sc1, sh1, h1n);
  k_gemm<128,128,1><<<dim3(32, 8), dim3(256), 0, stream>>>(h1n, w2b, b2, sc2, sh2, h2n);
  k_mlp3<<<dim3(32, 8), dim3(256), 0, stream>>>(h2n, w3b, b3, x, (float*)d_out);
}

// Round 6
// 230.188 us; speedup vs baseline: 1.1498x; 1.1498x over previous
//
#include <hip/hip_runtime.h>
#include <stdint.h>

#define B_ 8
#define C_ 256
#define N_ 2048
#define HC 128

typedef float f32x4 __attribute__((ext_vector_type(4)));
typedef short s16x8 __attribute__((ext_vector_type(8)));

__device__ __forceinline__ unsigned short f2bf(float f){
  union { float f; unsigned u; } v; v.f = f;
  unsigned r = v.u + 0x7FFF + ((v.u >> 16) & 1u);
  return (unsigned short)(r >> 16);
}
__device__ __forceinline__ float bf2f(unsigned short u){
  union { unsigned u; float f; } v; v.u = ((unsigned)u) << 16;
  return v.f;
}
__device__ __forceinline__ void gload_lds16(const void* g, void* l){
  __builtin_amdgcn_global_load_lds(
      (const __attribute__((address_space(1))) unsigned int*)g,
      (__attribute__((address_space(3))) unsigned int*)l, 16, 0, 0);
}

// ---------------- prep: weights -> bf16, BN affine fold ----------------
struct PrepArgs {
  const float *s0,*s1,*s2,*s3,*s4,*s5;
  unsigned short *d0,*d1,*d2,*d3,*d4,*d5;
  const float *b1,*g1,*be1,*m1,*v1;
  const float *b2,*g2,*be2,*m2,*v2;
  float *sc1,*sh1,*sc2,*sh2;
};

__global__ __launch_bounds__(256) void k_prep(PrepArgs a){
  int gid = blockIdx.x*256 + threadIdx.x;
  const int S0=65536, S1=131072, S2=196608, S3=229376, S4=245760, S5=278528;
  if (gid < S0)      a.d0[gid]    = f2bf(a.s0[gid]);
  else if (gid < S1) a.d1[gid-S0] = f2bf(a.s1[gid-S0]);
  else if (gid < S2) a.d2[gid-S1] = f2bf(a.s2[gid-S1]);
  else if (gid < S3) a.d3[gid-S2] = f2bf(a.s3[gid-S2]);
  else if (gid < S4) a.d4[gid-S3] = f2bf(a.s4[gid-S3]);
  else if (gid < S5) a.d5[gid-S4] = f2bf(a.s5[gid-S4]);
  else if (gid < S5+128){
    int o = gid - S5;
    float inv = a.g1[o] * rsqrtf(a.v1[o] + 1e-5f);
    a.sc1[o] = inv;
    a.sh1[o] = a.b1[o]*inv + a.be1[o] - a.m1[o]*inv;
  } else if (gid < S5+256){
    int o = gid - S5 - 128;
    float inv = a.g2[o] * rsqrtf(a.v2[o] + 1e-5f);
    a.sc2[o] = inv;
    a.sh2[o] = a.b2[o]*inv + a.be2[o] - a.m2[o]*inv;
  }
}

// ---------------- x [B][C][N] f32 -> xn [B][N][C] bf16 ----------------
__global__ __launch_bounds__(256) void k_transpose_x(const float* __restrict__ x,
                                                     unsigned short* __restrict__ xn){
  __shared__ float lds[64][65];
  int b = blockIdx.z, ct = blockIdx.y, nt = blockIdx.x;
  int n0 = nt*64, c0 = ct*64;
  const float* xb = x + (size_t)b*C_*N_;
  int tn = threadIdx.x & 63, tc0 = threadIdx.x >> 6;
  #pragma unroll
  for (int cc = tc0; cc < 64; cc += 4)
    lds[tn][cc] = xb[(size_t)(c0+cc)*N_ + n0 + tn];
  __syncthreads();
  unsigned short* xnb = xn + (size_t)b*N_*C_;
  int cl = threadIdx.x & 63, nl0 = threadIdx.x >> 6;
  #pragma unroll
  for (int nl = nl0; nl < 64; nl += 4)
    xnb[(size_t)(n0+nl)*C_ + c0 + cl] = f2bf(lds[nl][cl]);
}

// ---------------- QKV GEMM: xn @ W^T + b ----------------
__global__ __launch_bounds__(256) void k_qkv(
    const unsigned short* __restrict__ xn,
    const unsigned short* __restrict__ wqb, const unsigned short* __restrict__ wkb,
    const unsigned short* __restrict__ wvb,
    const float* __restrict__ bq, const float* __restrict__ bk, const float* __restrict__ bv,
    unsigned short* __restrict__ Qn, unsigned short* __restrict__ Kn,
    unsigned short* __restrict__ Vc)
{
  __shared__ unsigned short Alds[64][256];
  __shared__ unsigned short Tlds[64][260];
  int b = blockIdx.y, nt = blockIdx.x, z = blockIdx.z;
  int nb = nt*64;
  const unsigned short* W = (z==0) ? wqb : (z==1 ? wkb : wvb);
  const float* bias = (z==0) ? bq : (z==1 ? bk : bv);
  const unsigned short* Ab = xn + ((size_t)b*N_ + nb)*C_;
  for (int i = threadIdx.x; i < 64*32; i += 256){
    int r = i >> 5, cv = i & 31;
    *(s16x8*)&Alds[r][(cv*8) ^ ((r&7)<<3)] = *(const s16x8*)&Ab[(size_t)r*C_ + cv*8];
  }
  __syncthreads();
  int w = threadIdx.x >> 6, l = threadIdx.x & 63, lr = l & 15, lq = l >> 4;
  f32x4 acc[16];
  f32x4 zero = {0.f,0.f,0.f,0.f};
  #pragma unroll
  for (int i=0;i<16;i++) acc[i] = zero;
  #pragma unroll
  for (int ks = 0; ks < 8; ks++){
    s16x8 a = *(const s16x8*)&Alds[16*w + lr][(32*ks + 8*lq) ^ ((lr&7)<<3)];
    #pragma unroll
    for (int ct = 0; ct < 16; ct++){
      s16x8 bw = *(const s16x8*)&W[(size_t)(16*ct + lr)*C_ + 32*ks + 8*lq];
      acc[ct] = __builtin_amdgcn_mfma_f32_16x16x32_bf16(a, bw, acc[ct], 0, 0, 0);
    }
  }
  if (z < 2){
    unsigned short* ob = (z==0 ? Qn : Kn) + ((size_t)b*N_ + nb)*C_;
    #pragma unroll
    for (int ct = 0; ct < 16; ct++){
      int o = 16*ct + lr;
      float bi = bias[o];
      #pragma unroll
      for (int r = 0; r < 4; r++){
        int row = 16*w + 4*lq + r;
        ob[(size_t)row*C_ + o] = f2bf(acc[ct][r] + bi);
      }
    }
  } else {
    #pragma unroll
    for (int ct = 0; ct < 16; ct++){
      int o = 16*ct + lr;
      float bi = bias[o];
      #pragma unroll
      for (int r = 0; r < 4; r++)
        Tlds[16*w + 4*lq + r][o] = f2bf(acc[ct][r] + bi);
    }
    __syncthreads();
    unsigned short* vb = Vc + (size_t)b*C_*N_;
    int j = threadIdx.x & 63, o0 = threadIdx.x >> 6;
    #pragma unroll
    for (int o = o0; o < 256; o += 4)
      vb[(size_t)o*N_ + nb + j] = Tlds[j][o];
  }
}

// ---------------- attention: 8-wave blocks, XCD-local, async dbuf staging ----------------
// grid 512 linear blocks x 512 thr. Work swizzle: XCD x gets groups {x,x+8,x+16,x+24}
// = all 4 m-quarters of batch b=x -> K/V/Q of one batch (3MB) resident in XCD L2.
// KVBLK=32, QBLK=128 (8 waves x 16 rows). K/V double-buffered via global_load_lds
// with pre-swizzled source (linear LDS dest); one barrier per tile (implicit
// vmcnt(0) drain = pipeline wait). P = exp(S*beta) raw; bf16 partials -> k_merge.
__global__ __launch_bounds__(512, 4) void k_attn(
    const unsigned short* __restrict__ Qn, const unsigned short* __restrict__ Kn,
    const unsigned short* __restrict__ Vc, const float* __restrict__ beta,
    unsigned short* __restrict__ Opb, float* __restrict__ Ls)
{
  __shared__ unsigned short Klds[2][32][256];
  __shared__ unsigned short Vt[2][256][32];
  __shared__ unsigned short Plds[8][16][32];
  int tid = (int)threadIdx.x;
  // XCD-aware work mapping (bijective on [0,512))
  int bid = blockIdx.x;
  int x = bid & 7, j = bid >> 3;                 // j in [0,64)
  int W = ((x + 8*(j >> 4)) << 4) + (j & 15);    // group g = x+8*(j>>4), nt = j&15
  int nt = W & 15, g = W >> 4;
  int b = g & 7, mh = g >> 3;
  int nb = nt*128;
  const unsigned short* Qb = Qn + (size_t)b*N_*C_;
  const unsigned short* Kb = Kn + (size_t)b*N_*C_;
  const unsigned short* Vb = Vc + (size_t)b*C_*N_;
  const float* betab = beta + (size_t)b*N_*N_;
  int w = tid >> 6, l = tid & 63, lr = l & 15, lq = l >> 4;
  int wbase = (tid & ~63) * 16;                  // wave-uniform LDS byte base

  // Q fragments (regs, whole kernel)
  s16x8 qf[8];
  {
    const unsigned short* qrow = Qb + (size_t)(nb + 16*w + lr)*C_;
    #pragma unroll
    for (int ks = 0; ks < 8; ks++)
      qf[ks] = *(const s16x8*)&qrow[32*ks + 8*lq];
  }
  f32x4 zero = {0.f,0.f,0.f,0.f};
  f32x4 oacc[16];
  #pragma unroll
  for (int i=0;i<16;i++) oacc[i] = zero;
  float psum[4] = {0.f,0.f,0.f,0.f};

#define STAGE(BUF, MB)                                                        \
  {                                                                           \
    _Pragma("unroll")                                                         \
    for (int rr = 0; rr < 2; rr++){                                           \
      int i_ = rr*512 + tid;                                                  \
      int r_ = i_ >> 5, cv_ = i_ & 31;                                        \
      gload_lds16(&Kb[(size_t)((MB) + r_)*C_ + ((cv_*8) ^ ((r_&7)<<3))],      \
                  (char*)&Klds[BUF][0][0] + rr*8192 + wbase);                 \
    }                                                                         \
    _Pragma("unroll")                                                         \
    for (int rr = 0; rr < 2; rr++){                                           \
      int i_ = rr*512 + tid;                                                  \
      int c_ = i_ >> 2, mv_ = i_ & 3;                                         \
      gload_lds16(&Vb[(size_t)c_*N_ + (MB) + ((mv_*8) ^ ((c_&3)<<3))],        \
                  (char*)&Vt[BUF][0][0] + rr*8192 + wbase);                   \
    }                                                                         \
  }

  // prologue: stage tile 0
  STAGE(0, mh*512)
  __syncthreads();

  for (int mt = 0; mt < 16; mt++){
    int cur = mt & 1;
    int mb = mh*512 + mt*32;
    if (mt + 1 < 16){
      int mbn = mb + 32;
      STAGE(cur^1, mbn)
    }
    // beta for this tile (latency overlaps QK^T)
    float be[2][4];
    #pragma unroll
    for (int t4=0;t4<2;t4++)
      #pragma unroll
      for (int r=0;r<4;r++)
        be[t4][r] = betab[(size_t)(nb + 16*w + 4*lq + r)*N_ + mb + 16*t4 + lr];

    // S = Q K^T from LDS
    f32x4 s_[2];
    s_[0] = zero; s_[1] = zero;
    #pragma unroll
    for (int ks=0;ks<8;ks++){
      #pragma unroll
      for (int t4=0;t4<2;t4++){
        s16x8 bk_ = *(const s16x8*)&Klds[cur][16*t4 + lr][(32*ks + 8*lq) ^ ((lr&7)<<3)];
        s_[t4] = __builtin_amdgcn_mfma_f32_16x16x32_bf16(qf[ks], bk_, s_[t4], 0, 0, 0);
      }
    }
    // P = exp(S*beta); per-lane row-sums; pack to per-wave Plds
    #pragma unroll
    for (int t4=0;t4<2;t4++)
      #pragma unroll
      for (int r=0;r<4;r++){
        float p_ = __expf(s_[t4][r] * be[t4][r]);
        psum[r] += p_;
        int i_ = 4*lq + r;
        Plds[w][i_][(16*t4 + lr) ^ ((i_&3)<<3)] = f2bf(p_);
      }
    // PV: O += P * V from LDS (m-depth 32 -> single A-frag)
    {
      s16x8 ap_ = *(const s16x8*)&Plds[w][lr][(8*lq) ^ ((lr&3)<<3)];
      #pragma unroll
      for (int ct=0; ct<16; ct++){
        int c = 16*ct + lr;
        s16x8 bv_ = *(const s16x8*)&Vt[cur][c][(8*lq) ^ ((c&3)<<3)];
        oacc[ct] = __builtin_amdgcn_mfma_f32_16x16x32_bf16(ap_, bv_, oacc[ct], 0,0,0);
      }
    }
    __syncthreads();   // drains next-tile staging loads; releases cur buffer
  }
#undef STAGE

  // reduce row-sums across the 16-lane lr group (lanes share lq -> same rows)
  #pragma unroll
  for (int r=0;r<4;r++){
    #pragma unroll
    for (int d=1; d<16; d<<=1) psum[r] += __shfl_xor(psum[r], d, 64);
  }
  // store unnormalized partials as bf16 (normalization divides out quant noise)
  unsigned short* Ob = Opb + ((size_t)mh*8 + b)*(size_t)N_*C_;
  #pragma unroll
  for (int ct=0; ct<16; ct++)
    #pragma unroll
    for (int r=0;r<4;r++)
      Ob[(size_t)(nb + 16*w + 4*lq + r)*C_ + 16*ct + lr] = f2bf(oacc[ct][r]);
  if (lr == 0){
    float* Lb = Ls + ((size_t)mh*8 + b)*N_;
    #pragma unroll
    for (int r=0;r<4;r++) Lb[nb + 16*w + 4*lq + r] = psum[r];
  }
}

// ---------------- merge the four m-quarters, normalize, -> Mn bf16 ----------------
__global__ __launch_bounds__(256) void k_merge(
    const unsigned short* __restrict__ Opb, const float* __restrict__ Ls,
    unsigned short* __restrict__ Mn)
{
  int gid = blockIdx.x*256 + threadIdx.x;          // 8*2048*32 short8 chunks
  int c8 = gid & 31, n = (gid >> 5) & 2047, b = gid >> 16;
  size_t base = ((size_t)b*N_ + n)*C_ + c8*8;
  const size_t PS = (size_t)8*N_*C_;
  float acc[8] = {0.f,0.f,0.f,0.f,0.f,0.f,0.f,0.f};
  float lsum = 0.f;
  #pragma unroll
  for (int m=0;m<4;m++){
    s16x8 v = *(const s16x8*)&Opb[(size_t)m*PS + base];
    #pragma unroll
    for (int j=0;j<8;j++) acc[j] += bf2f((unsigned short)v[j]);
    lsum += Ls[((size_t)m*8 + b)*N_ + n];
  }
  float inv = 1.f / lsum;
  s16x8 o;
  #pragma unroll
  for (int j=0;j<8;j++) o[j] = (short)f2bf(acc[j] * inv);
  *(s16x8*)&Mn[base] = o;
}

// ---------------- generic NT GEMM: out[n][o] = epi(sum_c A[n][c] W[o][c]) ----------------
template<int CIN, int COUT, int MODE>
__global__ __launch_bounds__(256) void k_gemm(
    const unsigned short* __restrict__ A, const unsigned short* __restrict__ W,
    const float* __restrict__ bias, const float* __restrict__ sc,
    const float* __restrict__ sh, unsigned short* __restrict__ out)
{
  __shared__ unsigned short Alds[64][CIN];
  int b = blockIdx.y, nt = blockIdx.x, nb = nt*64;
  const unsigned short* Ab = A + ((size_t)b*N_ + nb)*CIN;
  constexpr int PR = CIN/8;
  for (int i = threadIdx.x; i < 64*PR; i += 256){
    int r = i / PR, cv = i % PR;
    *(s16x8*)&Alds[r][(cv*8) ^ ((r&7)<<3)] = *(const s16x8*)&Ab[(size_t)r*CIN + cv*8];
  }
  __syncthreads();
  int w = threadIdx.x >> 6, l = threadIdx.x & 63, lr = l & 15, lq = l >> 4;
  constexpr int NT = COUT/16;
  f32x4 acc[NT];
  f32x4 zero = {0.f,0.f,0.f,0.f};
  #pragma unroll
  for (int i=0;i<NT;i++) acc[i] = zero;
  #pragma unroll
  for (int ks = 0; ks < CIN/32; ks++){
    s16x8 a = *(const s16x8*)&Alds[16*w + lr][(32*ks + 8*lq) ^ ((lr&7)<<3)];
    #pragma unroll
    for (int ct = 0; ct < NT; ct++){
      s16x8 bw = *(const s16x8*)&W[(size_t)(16*ct + lr)*CIN + 32*ks + 8*lq];
      acc[ct] = __builtin_amdgcn_mfma_f32_16x16x32_bf16(a, bw, acc[ct], 0, 0, 0);
    }
  }
  unsigned short* ob = out + ((size_t)b*N_ + nb)*COUT;
  #pragma unroll
  for (int ct = 0; ct < NT; ct++){
    int o = 16*ct + lr;
    float bi = (MODE==0) ? bias[o] : 0.f;
    float s_ = (MODE==1) ? sc[o] : 0.f;
    float h_ = (MODE==1) ? sh[o] : 0.f;
    #pragma unroll
    for (int r = 0; r < 4; r++){
      int row = 16*w + 4*lq + r;
      float y;
      if (MODE==1) y = fmaxf(acc[ct][r]*s_ + h_, 0.f);
      else         y = acc[ct][r] + bi;
      ob[(size_t)row*COUT + o] = f2bf(y);
    }
  }
}

// ---------------- final: out[b][o][n] = x + h2n @ w3^T + b3 ----------------
__global__ __launch_bounds__(256) void k_mlp3(
    const unsigned short* __restrict__ A, const unsigned short* __restrict__ W,
    const float* __restrict__ b3, const float* __restrict__ x,
    float* __restrict__ out)
{
  __shared__ unsigned short Alds[64][128];
  __shared__ float Dlds[64][257];
  int b = blockIdx.y, nt = blockIdx.x, nb = nt*64;
  const unsigned short* Ab = A + ((size_t)b*N_ + nb)*HC;
  for (int i = threadIdx.x; i < 64*16; i += 256){
    int r = i >> 4, cv = i & 15;
    *(s16x8*)&Alds[r][(cv*8) ^ ((r&7)<<3)] = *(const s16x8*)&Ab[(size_t)r*HC + cv*8];
  }
  __syncthreads();
  int w = threadIdx.x >> 6, l = threadIdx.x & 63, lr = l & 15, lq = l >> 4;
  f32x4 acc[16];
  f32x4 zero = {0.f,0.f,0.f,0.f};
  #pragma unroll
  for (int i=0;i<16;i++) acc[i] = zero;
  #pragma unroll
  for (int ks = 0; ks < 4; ks++){
    s16x8 a = *(const s16x8*)&Alds[16*w + lr][(32*ks + 8*lq) ^ ((lr&7)<<3)];
    #pragma unroll
    for (int ct = 0; ct < 16; ct++){
      s16x8 bw = *(const s16x8*)&W[(size_t)(16*ct + lr)*HC + 32*ks + 8*lq];
      acc[ct] = __builtin_amdgcn_mfma_f32_16x16x32_bf16(a, bw, acc[ct], 0, 0, 0);
    }
  }
  #pragma unroll
  for (int ct = 0; ct < 16; ct++){
    int o = 16*ct + lr;
    float bi = b3[o];
    #pragma unroll
    for (int r = 0; r < 4; r++)
      Dlds[16*w + 4*lq + r][o] = acc[ct][r] + bi;
  }
  __syncthreads();
  const float* xb = x + (size_t)b*C_*N_;
  float* ob = out + (size_t)b*C_*N_;
  int j = threadIdx.x & 63, o0 = threadIdx.x >> 6;
  #pragma unroll
  for (int o = o0; o < 256; o += 4)
    ob[(size_t)o*N_ + nb + j] = xb[(size_t)o*N_ + nb + j] + Dlds[j][o];
}

extern "C" void kernel_launch(void* const* d_in, const int* in_sizes, int n_in,
                              void* d_out, int out_size, void* d_ws, size_t ws_size,
                              hipStream_t stream)
{
  const float* x    = (const float*)d_in[0];
  const float* beta = (const float*)d_in[1];
  const float* wq = (const float*)d_in[2];  const float* bq = (const float*)d_in[3];
  const float* wk = (const float*)d_in[4];  const float* bk = (const float*)d_in[5];
  const float* wv = (const float*)d_in[6];  const float* bv = (const float*)d_in[7];
  const float* w1 = (const float*)d_in[8];  const float* b1 = (const float*)d_in[9];
  const float* g1 = (const float*)d_in[10]; const float* be1= (const float*)d_in[11];
  const float* m1 = (const float*)d_in[12]; const float* v1 = (const float*)d_in[13];
  const float* w2 = (const float*)d_in[14]; const float* b2 = (const float*)d_in[15];
  const float* g2 = (const float*)d_in[16]; const float* be2= (const float*)d_in[17];
  const float* m2 = (const float*)d_in[18]; const float* v2 = (const float*)d_in[19];
  const float* w3 = (const float*)d_in[20]; const float* b3 = (const float*)d_in[21];

  char* p = (char*)d_ws;
  auto alloc = [&](size_t n){ char* r = p; p += (n + 255) & ~(size_t)255; return r; };
  unsigned short* xn  = (unsigned short*)alloc((size_t)B_*N_*C_*2);
  unsigned short* Qn  = (unsigned short*)alloc((size_t)B_*N_*C_*2);
  unsigned short* Kn  = (unsigned short*)alloc((size_t)B_*N_*C_*2);
  unsigned short* Vc  = (unsigned short*)alloc((size_t)B_*N_*C_*2);
  unsigned short* Mn  = (unsigned short*)alloc((size_t)B_*N_*C_*2);
  unsigned short* h1n = (unsigned short*)alloc((size_t)B_*N_*HC*2);
  unsigned short* h2n = (unsigned short*)alloc((size_t)B_*N_*HC*2);
  unsigned short* Opb = (unsigned short*)alloc((size_t)4*B_*N_*C_*2);
  float* Ls = (float*)alloc((size_t)4*B_*N_*4);
  unsigned short* wqb = (unsigned short*)alloc(65536*2);
  unsigned short* wkb = (unsigned short*)alloc(65536*2);
  unsigned short* wvb = (unsigned short*)alloc(65536*2);
  unsigned short* w1b = (unsigned short*)alloc(32768*2);
  unsigned short* w2b = (unsigned short*)alloc(16384*2);
  unsigned short* w3b = (unsigned short*)alloc(32768*2);
  float* sc1 = (float*)alloc(128*4);
  float* sh1 = (float*)alloc(128*4);
  float* sc2 = (float*)alloc(128*4);
  float* sh2 = (float*)alloc(128*4);

  PrepArgs pa;
  pa.s0 = wq; pa.s1 = wk; pa.s2 = wv; pa.s3 = w1; pa.s4 = w2; pa.s5 = w3;
  pa.d0 = wqb; pa.d1 = wkb; pa.d2 = wvb; pa.d3 = w1b; pa.d4 = w2b; pa.d5 = w3b;
  pa.b1 = b1; pa.g1 = g1; pa.be1 = be1; pa.m1 = m1; pa.v1 = v1;
  pa.b2 = b2; pa.g2 = g2; pa.be2 = be2; pa.m2 = m2; pa.v2 = v2;
  pa.sc1 = sc1; pa.sh1 = sh1; pa.sc2 = sc2; pa.sh2 = sh2;

  k_prep<<<dim3(1089), dim3(256), 0, stream>>>(pa);
  k_transpose_x<<<dim3(32, 4, 8), dim3(256), 0, stream>>>(x, xn);
  k_qkv<<<dim3(32, 8, 3), dim3(256), 0, stream>>>(xn, wqb, wkb, wvb, bq, bk, bv, Qn, Kn, Vc);
  k_attn<<<dim3(512), dim3(512), 0, stream>>>(Qn, Kn, Vc, beta, Opb, Ls);
  k_merge<<<dim3(2048), dim3(256), 0, stream>>>(Opb, Ls, Mn);
  k_gemm<256,128,1><<<dim3(32, 8), dim3(256), 0, stream>>>(Mn, w1b, b1, sc1, sh1, h1n);
  k_gemm<128,128,1><<<dim3(32, 8), dim3(256), 0, stream>>>(h1n, w2b, b2, sc2, sh2, h2n);
  k_mlp3<<<dim3(32, 8), dim3(256), 0, stream>>>(h2n, w3b, b3, x, (float*)d_out);
}